// Round 2
// baseline (158.555 us; speedup 1.0000x reference)
//
#include <hip/hip_runtime.h>
#include <math.h>

// FactorizationMachine: one wave (64 lanes) per output sample.
// index is sorted -> each sample's nonzeros are a contiguous segment found by
// binary search. Lanes stride the segment, accumulate {first, t1[16], t2[16]}
// in registers, butterfly-reduce across the wave, lane 0 writes sigmoid().

__global__ __launch_bounds__(256) void fm_kernel(
    const int* __restrict__ index,
    const int* __restrict__ feats,
    const float* __restrict__ values,
    const float* __restrict__ bias,
    const float* __restrict__ weights,
    const float* __restrict__ embedding,
    float* __restrict__ out,
    int nnz, int batch)
{
    const int wave = (int)((blockIdx.x * blockDim.x + threadIdx.x) >> 6);
    const int lane = (int)(threadIdx.x & 63);
    if (wave >= batch) return;
    const int b = wave;

    // lower_bound(index, b)
    int lo = 0, hi = nnz;
    while (lo < hi) {
        int mid = (lo + hi) >> 1;
        if (index[mid] < b) lo = mid + 1; else hi = mid;
    }
    const int start = lo;
    // lower_bound(index, b+1), restricted to [start, nnz)
    hi = nnz;
    while (lo < hi) {
        int mid = (lo + hi) >> 1;
        if (index[mid] < b + 1) lo = mid + 1; else hi = mid;
    }
    const int end = lo;

    float wsum = 0.0f;
    float t1[16], t2[16];
#pragma unroll
    for (int k = 0; k < 16; ++k) { t1[k] = 0.0f; t2[k] = 0.0f; }

    for (int i = start + lane; i < end; i += 64) {
        const int f = feats[i];
        const float v = values[i];
        wsum += weights[f] * v;
        const float4* erow = (const float4*)(embedding + (size_t)f * 16);
#pragma unroll
        for (int q = 0; q < 4; ++q) {
            float4 e = erow[q];
            float ev;
            ev = e.x * v; t1[4*q+0] += ev; t2[4*q+0] += ev * ev;
            ev = e.y * v; t1[4*q+1] += ev; t2[4*q+1] += ev * ev;
            ev = e.z * v; t1[4*q+2] += ev; t2[4*q+2] += ev * ev;
            ev = e.w * v; t1[4*q+3] += ev; t2[4*q+3] += ev * ev;
        }
    }

    // 64-lane butterfly reduction of all 33 partials
#pragma unroll
    for (int off = 32; off >= 1; off >>= 1) {
        wsum += __shfl_xor(wsum, off, 64);
#pragma unroll
        for (int k = 0; k < 16; ++k) {
            t1[k] += __shfl_xor(t1[k], off, 64);
            t2[k] += __shfl_xor(t2[k], off, 64);
        }
    }

    if (lane == 0) {
        float second = 0.0f;
#pragma unroll
        for (int k = 0; k < 16; ++k) second += t1[k] * t1[k] - t2[k];
        second *= 0.5f;
        const float x = wsum + bias[0] + second;
        out[b] = 1.0f / (1.0f + expf(-x));
    }
}

extern "C" void kernel_launch(void* const* d_in, const int* in_sizes, int n_in,
                              void* d_out, int out_size, void* d_ws, size_t ws_size,
                              hipStream_t stream) {
    // setup_inputs order: batch_size, index, feats, values, bias, weights, embedding
    const int*   index     = (const int*)d_in[1];
    const int*   feats     = (const int*)d_in[2];
    const float* values    = (const float*)d_in[3];
    const float* bias      = (const float*)d_in[4];
    const float* weights   = (const float*)d_in[5];
    const float* embedding = (const float*)d_in[6];
    float* out = (float*)d_out;

    const int nnz   = in_sizes[1];
    const int batch = out_size;      // output is (1, BATCH)

    const int waves_per_block = 4;   // 256 threads
    const int blocks = (batch + waves_per_block - 1) / waves_per_block;
    fm_kernel<<<blocks, 256, 0, stream>>>(index, feats, values, bias, weights,
                                          embedding, out, nnz, batch);
}

// Round 3
// 141.896 us; speedup vs baseline: 1.1174x; 1.1174x over previous
//
#include <hip/hip_runtime.h>
#include <math.h>

// FactorizationMachine v2.
// Kernel 1: seg_starts — index is sorted; thread i writes starts[b]=i for all
//           b in (index[i-1], index[i]]; thread nnz-1 also closes the tail.
//           Removes 2 binary searches (≈40 dependent loads) per wave.
// Kernel 2: fm2 — one wave per sample. Lane = (j<<4)|k, j∈[0,4) items/iter,
//           k∈[0,16) embedding column. t1/t2 lane-local; reduction = 10 shuffles.

__global__ __launch_bounds__(256) void seg_starts(
    const int* __restrict__ index, int* __restrict__ starts, int nnz, int batch)
{
    const int i = blockIdx.x * blockDim.x + threadIdx.x;
    if (i >= nnz) return;
    const int cur  = index[i];
    const int prev = (i == 0) ? -1 : index[i - 1];
    for (int b = prev + 1; b <= cur; ++b) starts[b] = i;
    if (i == nnz - 1) {
        for (int b = cur + 1; b <= batch; ++b) starts[b] = nnz;
    }
}

template<int USE_STARTS>
__global__ __launch_bounds__(256) void fm2(
    const int* __restrict__ index,
    const int* __restrict__ feats,
    const float* __restrict__ values,
    const float* __restrict__ bias,
    const float* __restrict__ weights,
    const float* __restrict__ embedding,
    const int* __restrict__ starts,
    float* __restrict__ out,
    int nnz, int batch)
{
    const int wave = blockIdx.x * 4 + (int)(threadIdx.x >> 6);
    const int lane = (int)(threadIdx.x & 63);
    if (wave >= batch) return;
    const int b = wave;

    int start, end;
    if (USE_STARTS) {
        start = starts[b];
        end   = starts[b + 1];
    } else {
        int lo = 0, hi = nnz;
        while (lo < hi) { int m = (lo + hi) >> 1; if (index[m] < b) lo = m + 1; else hi = m; }
        start = lo; hi = nnz;
        while (lo < hi) { int m = (lo + hi) >> 1; if (index[m] < b + 1) lo = m + 1; else hi = m; }
        end = lo;
    }

    const int k = lane & 15;   // embedding column owned by this lane
    const int j = lane >> 4;   // item slot within a 4-item iteration

    float t1 = 0.0f, t2 = 0.0f, ws = 0.0f;
    for (int i0 = start; i0 < end; i0 += 4) {
        const int i = i0 + j;
        if (i < end) {
            const int f   = feats[i];            // broadcast across 16 lanes
            const float v = values[i];           // broadcast
            const float e = embedding[(size_t)f * 16 + k];  // 64B line / item
            const float ev = e * v;
            t1 += ev;
            t2 += ev * ev;
            ws += weights[f] * v;                // broadcast; j-reduced only
        }
    }

    // reduce across the 4 j-groups (every lane ends with its k's full totals)
    t1 += __shfl_xor(t1, 16, 64); t1 += __shfl_xor(t1, 32, 64);
    t2 += __shfl_xor(t2, 16, 64); t2 += __shfl_xor(t2, 32, 64);
    ws += __shfl_xor(ws, 16, 64); ws += __shfl_xor(ws, 32, 64);
    // ws is now the full first-order sum, identical in all lanes (no k-reduce!)

    // second-order: sum over k of (t1_k^2 - t2_k) within the 16-lane group
    float sec = t1 * t1 - t2;
    sec += __shfl_xor(sec, 1, 64);
    sec += __shfl_xor(sec, 2, 64);
    sec += __shfl_xor(sec, 4, 64);
    sec += __shfl_xor(sec, 8, 64);

    if (lane == 0) {
        const float x = ws + bias[0] + 0.5f * sec;
        out[b] = 1.0f / (1.0f + expf(-x));
    }
}

extern "C" void kernel_launch(void* const* d_in, const int* in_sizes, int n_in,
                              void* d_out, int out_size, void* d_ws, size_t ws_size,
                              hipStream_t stream) {
    // setup_inputs order: batch_size, index, feats, values, bias, weights, embedding
    const int*   index     = (const int*)d_in[1];
    const int*   feats     = (const int*)d_in[2];
    const float* values    = (const float*)d_in[3];
    const float* bias      = (const float*)d_in[4];
    const float* weights   = (const float*)d_in[5];
    const float* embedding = (const float*)d_in[6];
    float* out = (float*)d_out;

    const int nnz   = in_sizes[1];
    const int batch = out_size;               // output is (1, BATCH)
    const int fm_blocks = (batch + 3) / 4;    // 4 waves (samples) per block

    if (ws_size >= (size_t)(batch + 1) * sizeof(int)) {
        int* starts = (int*)d_ws;
        seg_starts<<<(nnz + 255) / 256, 256, 0, stream>>>(index, starts, nnz, batch);
        fm2<1><<<fm_blocks, 256, 0, stream>>>(index, feats, values, bias, weights,
                                              embedding, starts, out, nnz, batch);
    } else {
        fm2<0><<<fm_blocks, 256, 0, stream>>>(index, feats, values, bias, weights,
                                              embedding, nullptr, out, nnz, batch);
    }
}

// Round 4
// 133.068 us; speedup vs baseline: 1.1915x; 1.0663x over previous
//
#include <hip/hip_runtime.h>
#include <math.h>

// FactorizationMachine v3.
// seg_starts: index sorted -> starts[] segment boundaries (one pass, no search).
// fm3: one wave per sample. Two-phase per 128-item chunk:
//   Phase A (preload): 64 lanes coalesced-load feats/values -> LDS, and fold
//     the ENTIRE first-order term ws += weights[f]*v (one independent gather
//     per lane). Removes weights + feats/values from the inner loop.
//   Phase B (gather): lane = (j<<4)|k ; group j reads (f,v) for item 4t+j from
//     LDS (fast, fixed latency) and issues an independent embedding gather.
//     Only a 1-deep HBM chain -> high MLP, latency hidden by occupancy.

__global__ __launch_bounds__(256) void seg_starts(
    const int* __restrict__ index, int* __restrict__ starts, int nnz, int batch)
{
    const int i = blockIdx.x * blockDim.x + threadIdx.x;
    if (i >= nnz) return;
    const int cur  = index[i];
    const int prev = (i == 0) ? -1 : index[i - 1];
    for (int b = prev + 1; b <= cur; ++b) starts[b] = i;
    if (i == nnz - 1) {
        for (int b = cur + 1; b <= batch; ++b) starts[b] = nnz;
    }
}

__global__ __launch_bounds__(256) void fm3(
    const int* __restrict__ feats,
    const float* __restrict__ values,
    const float* __restrict__ bias,
    const float* __restrict__ weights,
    const float* __restrict__ embedding,
    const int* __restrict__ starts,
    float* __restrict__ out,
    int batch)
{
    __shared__ int2 buf[4][128];           // {feat, bits(value)} per item, 4 KB

    const int wslot = (int)(threadIdx.x >> 6);
    const int wave  = blockIdx.x * 4 + wslot;
    const int lane  = (int)(threadIdx.x & 63);
    if (wave >= batch) return;
    const int b = wave;

    const int start = starts[b];
    const int end   = starts[b + 1];

    const int k = lane & 15;               // embedding column owned by this lane
    const int j = lane >> 4;               // item slot within a 4-item step

    float t1 = 0.0f, t2 = 0.0f, ws = 0.0f;

    for (int base = start; base < end; base += 128) {
        const int cnt = min(end - base, 128);

        // ---- Phase A: coalesced preload + first-order term ----
        if (lane < cnt) {
            const int   f = feats[base + lane];
            const float v = values[base + lane];
            buf[wslot][lane] = make_int2(f, __float_as_int(v));
            ws += weights[f] * v;          // independent gather, off critical path
        }
        const int i2 = lane + 64;
        if (i2 < cnt) {
            const int   f = feats[base + i2];
            const float v = values[base + i2];
            buf[wslot][i2] = make_int2(f, __float_as_int(v));
            ws += weights[f] * v;
        }
        // wave-local LDS produce->consume ordering (no cross-wave sync needed)
        asm volatile("s_waitcnt lgkmcnt(0)" ::: "memory");

        // ---- Phase B: independent embedding gathers ----
#pragma unroll 2
        for (int t0 = 0; t0 < cnt; t0 += 4) {
            const int item = t0 + j;
            if (item < cnt) {
                const int2 fv = buf[wslot][item];
                const int   f = fv.x;
                const float v = __int_as_float(fv.y);
                const float e  = embedding[(size_t)f * 16 + k]; // 64B line / item
                const float ev = e * v;
                t1 += ev;
                t2 += ev * ev;
            }
        }
    }

    // j-reduce t1/t2 (each lane keeps its column k's totals)
    t1 += __shfl_xor(t1, 16, 64); t1 += __shfl_xor(t1, 32, 64);
    t2 += __shfl_xor(t2, 16, 64); t2 += __shfl_xor(t2, 32, 64);

    // full-wave reduce of first-order partials (each item counted once)
    ws += __shfl_xor(ws, 1, 64);  ws += __shfl_xor(ws, 2, 64);
    ws += __shfl_xor(ws, 4, 64);  ws += __shfl_xor(ws, 8, 64);
    ws += __shfl_xor(ws, 16, 64); ws += __shfl_xor(ws, 32, 64);

    // second order: sum_k (t1_k^2 - t2_k) within the 16-lane group
    float sec = t1 * t1 - t2;
    sec += __shfl_xor(sec, 1, 64);
    sec += __shfl_xor(sec, 2, 64);
    sec += __shfl_xor(sec, 4, 64);
    sec += __shfl_xor(sec, 8, 64);

    if (lane == 0) {
        const float x = ws + bias[0] + 0.5f * sec;
        out[b] = 1.0f / (1.0f + expf(-x));
    }
}

extern "C" void kernel_launch(void* const* d_in, const int* in_sizes, int n_in,
                              void* d_out, int out_size, void* d_ws, size_t ws_size,
                              hipStream_t stream) {
    // setup_inputs order: batch_size, index, feats, values, bias, weights, embedding
    const int*   index     = (const int*)d_in[1];
    const int*   feats     = (const int*)d_in[2];
    const float* values    = (const float*)d_in[3];
    const float* bias      = (const float*)d_in[4];
    const float* weights   = (const float*)d_in[5];
    const float* embedding = (const float*)d_in[6];
    float* out = (float*)d_out;

    const int nnz   = in_sizes[1];
    const int batch = out_size;               // output is (1, BATCH)

    int* starts = (int*)d_ws;                 // batch+1 ints, ws is plenty
    seg_starts<<<(nnz + 255) / 256, 256, 0, stream>>>(index, starts, nnz, batch);

    const int fm_blocks = (batch + 3) / 4;    // 4 waves (samples) per block
    fm3<<<fm_blocks, 256, 0, stream>>>(feats, values, bias, weights,
                                       embedding, starts, out, batch);
}

// Round 5
// 126.695 us; speedup vs baseline: 1.2515x; 1.0503x over previous
//
#include <hip/hip_runtime.h>
#include <math.h>

// FactorizationMachine v4.
// seg_starts: index sorted -> starts[] segment boundaries (one pass).
// fm4: one wave per sample, lane=(j<<4)|k. Phase A: coalesced preload of
//   (f,v) into LDS + first-order fold (weights gather off critical path).
//   Phase B: explicit 4-deep gather batches -> 4 independent embedding-row
//   loads in flight per lane (Little's law: need ~144 outstanding 64B reqs
//   per CU to saturate HBM; 2-deep wasn't enough). Branchless tail.

__global__ __launch_bounds__(256) void seg_starts(
    const int* __restrict__ index, int* __restrict__ starts, int nnz, int batch)
{
    const int i = blockIdx.x * blockDim.x + threadIdx.x;
    if (i >= nnz) return;
    const int cur  = index[i];
    const int prev = (i == 0) ? -1 : index[i - 1];
    for (int b = prev + 1; b <= cur; ++b) starts[b] = i;
    if (i == nnz - 1) {
        for (int b = cur + 1; b <= batch; ++b) starts[b] = nnz;
    }
}

__global__ __launch_bounds__(256) void fm4(
    const int* __restrict__ feats,
    const float* __restrict__ values,
    const float* __restrict__ bias,
    const float* __restrict__ weights,
    const float* __restrict__ embedding,
    const int* __restrict__ starts,
    float* __restrict__ out,
    int batch)
{
    __shared__ int2 buf[4][128];           // {feat, bits(value)}, 4 KB/block

    const int wslot = (int)(threadIdx.x >> 6);
    const int wave  = blockIdx.x * 4 + wslot;
    const int lane  = (int)(threadIdx.x & 63);
    if (wave >= batch) return;
    const int b = wave;

    const int start = starts[b];
    const int end   = starts[b + 1];

    const int k = lane & 15;               // embedding column owned by this lane
    const int j = lane >> 4;               // item slot within a 16-item step

    float t1 = 0.0f, t2 = 0.0f, ws = 0.0f;

    for (int base = start; base < end; base += 128) {
        const int cnt = min(end - base, 128);

        // ---- Phase A: coalesced preload + first-order term ----
        if (lane < cnt) {
            const int   f = feats[base + lane];
            const float v = values[base + lane];
            buf[wslot][lane] = make_int2(f, __float_as_int(v));
            ws += weights[f] * v;          // independent gather, off critical path
        }
        const int i2 = lane + 64;
        if (i2 < cnt) {
            const int   f = feats[base + i2];
            const float v = values[base + i2];
            buf[wslot][i2] = make_int2(f, __float_as_int(v));
            ws += weights[f] * v;
        }
        // wave-local LDS produce->consume ordering (no cross-wave sync needed)
        asm volatile("s_waitcnt lgkmcnt(0)" ::: "memory");

        // ---- Phase B: 4-deep independent embedding gathers ----
        for (int t0 = 0; t0 < cnt; t0 += 16) {
            int   f[4]; float v[4];
#pragma unroll
            for (int u = 0; u < 4; ++u) {
                const int item = t0 + j + 4 * u;
                const int2 fv = buf[wslot][item < cnt ? item : 0];
                f[u] = fv.x;
                v[u] = (item < cnt) ? __int_as_float(fv.y) : 0.0f;  // branchless tail
            }
            float e[4];
#pragma unroll
            for (int u = 0; u < 4; ++u)
                e[u] = embedding[(size_t)f[u] * 16 + k];   // 4 loads in flight
#pragma unroll
            for (int u = 0; u < 4; ++u) {
                const float ev = e[u] * v[u];
                t1 += ev;
                t2 += ev * ev;
            }
        }
    }

    // j-reduce t1/t2 (each lane keeps its column k's totals)
    t1 += __shfl_xor(t1, 16, 64); t1 += __shfl_xor(t1, 32, 64);
    t2 += __shfl_xor(t2, 16, 64); t2 += __shfl_xor(t2, 32, 64);

    // full-wave reduce of first-order partials (each item counted once)
    ws += __shfl_xor(ws, 1, 64);  ws += __shfl_xor(ws, 2, 64);
    ws += __shfl_xor(ws, 4, 64);  ws += __shfl_xor(ws, 8, 64);
    ws += __shfl_xor(ws, 16, 64); ws += __shfl_xor(ws, 32, 64);

    // second order: sum_k (t1_k^2 - t2_k) within the 16-lane group
    float sec = t1 * t1 - t2;
    sec += __shfl_xor(sec, 1, 64);
    sec += __shfl_xor(sec, 2, 64);
    sec += __shfl_xor(sec, 4, 64);
    sec += __shfl_xor(sec, 8, 64);

    if (lane == 0) {
        const float x = ws + bias[0] + 0.5f * sec;
        out[b] = 1.0f / (1.0f + expf(-x));
    }
}

extern "C" void kernel_launch(void* const* d_in, const int* in_sizes, int n_in,
                              void* d_out, int out_size, void* d_ws, size_t ws_size,
                              hipStream_t stream) {
    // setup_inputs order: batch_size, index, feats, values, bias, weights, embedding
    const int*   index     = (const int*)d_in[1];
    const int*   feats     = (const int*)d_in[2];
    const float* values    = (const float*)d_in[3];
    const float* bias      = (const float*)d_in[4];
    const float* weights   = (const float*)d_in[5];
    const float* embedding = (const float*)d_in[6];
    float* out = (float*)d_out;

    const int nnz   = in_sizes[1];
    const int batch = out_size;               // output is (1, BATCH)

    int* starts = (int*)d_ws;                 // batch+1 ints, ws is plenty
    seg_starts<<<(nnz + 255) / 256, 256, 0, stream>>>(index, starts, nnz, batch);

    const int fm_blocks = (batch + 3) / 4;    // 4 waves (samples) per block
    fm4<<<fm_blocks, 256, 0, stream>>>(feats, values, bias, weights,
                                       embedding, starts, out, batch);
}